// Round 15
// baseline (1424.518 us; speedup 1.0000x reference)
//
#include <hip/hip_runtime.h>

// Custom LSTM scan.  B=64, L=512, P=64, A=16, D=512, F=80.
//   h_t = h_{t-1} + tanh(x_t W_ci + b_ci) * sigmoid(h_{t-1} R_ig + b_ig)
//
// R20: SINGLE WG PER ROW (no cross-WG exchange), R split in BALANCED
// on-chip tiers.  The 2-WG design is at its latency floor (V~1900cy
// fabric visibility, probed 4 ways; identical scan code measured 533 vs
// 593us across sessions -> only structural changes are measurable).
// Round-0 baseline failed because rr[32] never got registers (VGPR=128
// -> spill -> 18.6GB refetch, 3750cy/step); R16 failed because 19 LDS
// chunks put ~2600cy on the DS pipe.  Balanced residency per thread
// (64 uint4 chunks of R):
//   jc  0..31 -> AGPR   (32 chunks, 128 a-regs, "+a" pins)
//   jc 32..40 -> VGPR   ( 9 chunks,  36 v-regs, "+v" pins)
//   jc 41..50 -> LDS    (10 chunks, 80KB; DS/step = (10+8)x8x12 ~1728cy)
//   jc 51..63 -> L2 stream (13 chunks; R is step-invariant + L2-resident
//                -> pure BW ~470B/cy/XCD vs ~1900 available; latency
//                hidden under the AGPR-dot phases)
// VGPR peak ~124 <= 128 @ 2 waves/SIMD (unified V+A pool 512/SIMD).
// Scan structure (8-lane k-slices, DPP reduce-scatter, swizzled hp, two
// barriers/step, outbuf epilogue) is the round-0 PROVEN kernel verbatim.
// prep+ci merged (R19, proven), CI_R=32.

#define B_  64
#define L_  512
#define P_  64
#define A_  16
#define D_  512
#define F_  80
#define CI_R 32

#define NLDS 10
#define SMEM_BYTES (NLDS * D_ * 16 + 1024 + 32 + 2048)   // 85,024 B
#define CI_BYTES   ((size_t)B_ * L_ * D_ * 2)            // 33,554,432

typedef _Float16 half2_t __attribute__((ext_vector_type(2)));
typedef unsigned int uintx4 __attribute__((ext_vector_type(4)));

__device__ __forceinline__ float dot2(unsigned int r, unsigned int h, float acc) {
    return __builtin_amdgcn_fdot2(__builtin_bit_cast(half2_t, h),
                                  __builtin_bit_cast(half2_t, r), acc, false);
}
__device__ __forceinline__ float dot4u(uintx4 r, uintx4 h, float acc) {
    acc = dot2(r.x, h.x, acc);
    acc = dot2(r.y, h.y, acc);
    acc = dot2(r.z, h.z, acc);
    acc = dot2(r.w, h.w, acc);
    return acc;
}
template<int CTRL>
__device__ __forceinline__ float dpp_mov(float v) {
    return __builtin_bit_cast(float, __builtin_amdgcn_update_dpp(
        0, __builtin_bit_cast(int, v), CTRL, 0xF, 0xF, true));
}
// DPP ctrls: quad_perm(1,0,3,2)=0xB1 (xor1), quad_perm(2,3,0,1)=0x4E (xor2),
// row_half_mirror=0x141 (xor7), row_mirror=0x140 (xor15),
// row_bcast15=0x142, row_bcast31=0x143.

// Merged prep+ci.  Blocks < 512: pack R_ig fp32[k][d] -> f16-pair uint
// chunks laid out [w][jc][l][q] (round-0 layout): uint4 (w,jc,l) with
// j=jc>>3, c=jc&7 holds pairs p = g*32+c*4+{0..3} (k=2p,2p+1) of column
// d = w*64 + (l>>3)*8 + j, where g = l&7.
// Blocks >= 512: ci = tanh(x @ W_ci + b_ci) f16, CI_R rows per block.
__global__ __launch_bounds__(256) void prep_kernel(const float* __restrict__ R,
        const float* __restrict__ obs, const float* __restrict__ act,
        const float* __restrict__ Wci, const float* __restrict__ bci,
        unsigned int* __restrict__ Rp, unsigned short* __restrict__ ci) {
    int blk = blockIdx.x;
    int tid = threadIdx.x;
    if (blk < 512) {
        int id = blk * 256 + tid;                      // 131072 uints
        int q = id & 3;
        int l = (id >> 2) & 63;
        int c = (id >> 8) & 7;
        int j = (id >> 11) & 7;
        int w = id >> 14;
        int r = l >> 3, g = l & 7;
        int d = w * 64 + r * 8 + j;
        int p = g * 32 + c * 4 + q;
        int k0 = 2 * p;
        half2_t v;
        v.x = (_Float16)R[k0 * D_ + d];
        v.y = (_Float16)R[(k0 + 1) * D_ + d];
        Rp[id] = __builtin_bit_cast(unsigned int, v);
        return;
    }
    // ---- ci part ----
    __shared__ float xs[CI_R][F_];
    int row0 = (blk - 512) * CI_R;
    for (int idx = tid; idx < CI_R * F_; idx += 256) {
        int r = idx / F_, f = idx % F_;
        float v = (f < P_) ? obs[(size_t)(row0 + r) * P_ + f]
                           : act[(size_t)(row0 + r) * A_ + (f - P_)];
        xs[r][f] = v;
    }
    __syncthreads();
    int d0 = tid, d1 = tid + 256;
    float a0[CI_R], a1[CI_R];
    #pragma unroll
    for (int r = 0; r < CI_R; ++r) { a0[r] = 0.f; a1[r] = 0.f; }
    for (int f = 0; f < F_; ++f) {
        float w0 = Wci[f * D_ + d0];
        float w1 = Wci[f * D_ + d1];
        #pragma unroll
        for (int r = 0; r < CI_R; ++r) {
            float xv = xs[r][f];
            a0[r] += xv * w0;
            a1[r] += xv * w1;
        }
    }
    float b0 = bci[d0], b1 = bci[d1];
    #pragma unroll
    for (int r = 0; r < CI_R; ++r) {
        float z0 = a0[r] + b0, z1 = a1[r] + b1;
        float e0 = __expf(-2.f * __builtin_fabsf(z0));
        float e1 = __expf(-2.f * __builtin_fabsf(z1));
        float m0 = (1.f - e0) * __builtin_amdgcn_rcpf(1.f + e0);
        float m1 = (1.f - e1) * __builtin_amdgcn_rcpf(1.f + e1);
        float t0 = z0 < 0.f ? -m0 : m0;
        float t1 = z1 < 0.f ? -m1 : m1;
        ci[(size_t)(row0 + r) * D_ + d0] = __builtin_bit_cast(unsigned short, (_Float16)t0);
        ci[(size_t)(row0 + r) * D_ + d1] = __builtin_bit_cast(unsigned short, (_Float16)t1);
    }
}

// Serial scan.  One block per batch row.  Thread (w=tid>>6, l=tid&63):
// g=l&7; computes partials over k in [g*64,g*64+64) for outputs
// d = w*64 + (l>>3)*8 + j, j=0..7; DPP reduce-scatter leaves lane with
// j=g -> thread owns d = tid.  Chunk residency per header comment.
__global__ __launch_bounds__(512)
__attribute__((amdgpu_waves_per_eu(2, 2)))
void scan_kernel(
    const uintx4* __restrict__ Rp, const unsigned short* __restrict__ ci,
    const float* __restrict__ b_ig, const float* __restrict__ W_out,
    const float* __restrict__ b_out, float* __restrict__ out)
{
    const int tid = threadIdx.x;
    const int b = blockIdx.x;
    const int w = tid >> 6;
    const int l = tid & 63;
    const int g = l & 7;

    extern __shared__ __align__(16) char smem[];
    uintx4* ldsR = (uintx4*)smem;                                 // 10*512*16 B
    unsigned int* hp = (unsigned int*)(smem + NLDS * D_ * 16);    // 1024 B
    float* red = (float*)(smem + NLDS * D_ * 16 + 1024);          // 32 B
    float* outbuf = (float*)(smem + NLDS * D_ * 16 + 1056);       // 2048 B

    const uintx4* tb = Rp + (w << 12) + l;   // chunk jc at tb[jc*64]

    // AGPR tier: jc 0..31 (128 a-regs)
    uintx4 ra[32];
    #pragma unroll
    for (int i = 0; i < 32; ++i) ra[i] = tb[i * 64];
    #pragma unroll
    for (int i = 0; i < 32; ++i) asm volatile("" : "+a"(ra[i]));

    // VGPR tier: jc 32..40 (36 v-regs)
    uintx4 rv[9];
    #pragma unroll
    for (int i = 0; i < 9; ++i) rv[i] = tb[(32 + i) * 64];
    #pragma unroll
    for (int i = 0; i < 9; ++i) asm volatile("" : "+v"(rv[i]));

    // LDS tier: jc 41..50
    #pragma unroll
    for (int i = 0; i < NLDS; ++i) ldsR[i * D_ + tid] = tb[(41 + i) * 64];
    if (tid < 256) hp[tid] = 0u;

    float hval = 0.f;                      // h[tid], fp32, persistent
    const float bg = b_ig[tid];
    const float wo = W_out[tid];
    const float bo = b_out[0];
    const unsigned short* cip = ci + (size_t)b * L_ * D_ + tid;

    // swizzled h write slot: uint4 index i=tid>>3 has (g_i=w, c_i=(tid>>3)&7);
    // stored at slot (g_i<<3)|((c_i+g_i)&7) so broadcast reads are conflict-free
    const int wslot = (((w << 3) | ((((tid >> 3) & 7) + w) & 7)) << 2) | ((tid >> 1) & 3);

    __syncthreads();

    const uintx4* hp4s = (const uintx4*)hp;

    #pragma unroll 1
    for (int t = 0; t < L_; ++t) {
        unsigned short cu = cip[t * D_];

        // issue stream group A (jc 51..57) -- L2-resident, consumed after
        // the AGPR dot phase (latency covered)
        uintx4 sa[7];
        #pragma unroll
        for (int i = 0; i < 7; ++i) sa[i] = tb[(51 + i) * 64];

        // h slice (8 uint4) from swizzled LDS: slot (g<<3)|((c+g)&7)
        uintx4 hsr[8];
        #pragma unroll
        for (int c = 0; c < 8; ++c) hsr[c] = hp4s[(g << 3) | ((c + g) & 7)];

        float p[8];
        #pragma unroll
        for (int j = 0; j < 8; ++j) p[j] = 0.f;

        // AGPR chunks jc 0..31 -> p[0..3] (covers A's L2 latency)
        #pragma unroll
        for (int i = 0; i < 32; ++i)
            p[i >> 3] = dot4u(ra[i], hsr[i & 7], p[i >> 3]);

        // consume A: jc 51..55 -> p[6]; jc 56,57 -> p[7]
        #pragma unroll
        for (int i = 0; i < 7; ++i) {
            int jc = 51 + i;
            p[jc >> 3] = dot4u(sa[i], hsr[jc & 7], p[jc >> 3]);
        }

        // issue stream group B (jc 58..63)
        uintx4 sb[6];
        #pragma unroll
        for (int i = 0; i < 6; ++i) sb[i] = tb[(58 + i) * 64];

        // VGPR chunks jc 32..40 -> p[4], p[5]
        #pragma unroll
        for (int i = 0; i < 9; ++i) {
            int jc = 32 + i;
            p[jc >> 3] = dot4u(rv[i], hsr[jc & 7], p[jc >> 3]);
        }

        // LDS chunks jc 41..50 -> p[5], p[6]
        #pragma unroll
        for (int i = 0; i < NLDS; ++i) {
            int jc = 41 + i;
            p[jc >> 3] = dot4u(ldsR[i * D_ + tid], hsr[jc & 7], p[jc >> 3]);
        }

        // consume B: jc 58..63 -> p[7]
        #pragma unroll
        for (int i = 0; i < 6; ++i) {
            int jc = 58 + i;
            p[jc >> 3] = dot4u(sb[i], hsr[jc & 7], p[jc >> 3]);
        }

        // reduce-scatter over the 8-lane slice group (all DPP):
        float q0[4];
        #pragma unroll
        for (int i = 0; i < 4; ++i) {
            float a = p[i] + dpp_mov<0x141>(p[i]);       // xor7
            float c2 = p[i + 4] + dpp_mov<0x141>(p[i + 4]);
            q0[i] = (g & 4) ? c2 : a;
        }
        float r0a = q0[0] + dpp_mov<0xB1>(q0[0]);        // xor1
        float r0b = q0[1] + dpp_mov<0xB1>(q0[1]);
        float r1a = q0[2] + dpp_mov<0xB1>(q0[2]);
        float r1b = q0[3] + dpp_mov<0xB1>(q0[3]);
        float r0 = (g & 1) ? r0b : r0a;
        float r1 = (g & 1) ? r1b : r1a;
        float za = r0 + dpp_mov<0x4E>(r0);               // xor2
        float zb = r1 + dpp_mov<0x4E>(r1);
        float z = (g & 2) ? zb : za;                     // z for d = tid

        float zz = z + bg;
        float ig = __builtin_amdgcn_rcpf(1.f + __expf(-zz));
        float civ = (float)__builtin_bit_cast(_Float16, cu);
        hval += civ * ig;

        // wave-reduce hval*wo via DPP (sum lands in lane 63)
        float po = hval * wo;
        po += dpp_mov<0xB1>(po);
        po += dpp_mov<0x4E>(po);
        po += dpp_mov<0x141>(po);
        po += dpp_mov<0x140>(po);
        po += dpp_mov<0x142>(po);
        po += dpp_mov<0x143>(po);

        float nbh = dpp_mov<0xB1>(hval);  // neighbor (lane^1) h

        __syncthreads();                  // all reads of old hp complete
        if ((tid & 1) == 0) {
            hp[wslot] = __builtin_bit_cast(unsigned int,
                            __builtin_amdgcn_cvt_pkrtz(hval, nbh));
        }
        if (l == 63) red[w] = po;
        __syncthreads();                  // new hp + partials visible
        if (tid == 0) {
            outbuf[t] = red[0] + red[1] + red[2] + red[3] +
                        red[4] + red[5] + red[6] + red[7] + bo;
        }
    }
    __syncthreads();
    out[b * L_ + tid] = outbuf[tid];
}

extern "C" void kernel_launch(void* const* d_in, const int* in_sizes, int n_in,
                              void* d_out, int out_size, void* d_ws, size_t ws_size,
                              hipStream_t stream) {
    const float* obs   = (const float*)d_in[0];
    const float* act   = (const float*)d_in[1];
    const float* W_ci  = (const float*)d_in[2];
    const float* b_ci  = (const float*)d_in[3];
    const float* R_ig  = (const float*)d_in[4];
    const float* b_ig  = (const float*)d_in[5];
    const float* W_out = (const float*)d_in[6];
    const float* b_out = (const float*)d_in[7];
    float* out = (float*)d_out;

    unsigned short* ci = (unsigned short*)d_ws;                        // 32 MB f16
    unsigned int* Rp = (unsigned int*)((char*)d_ws + CI_BYTES);

    // host-side config (not a stream op; graph-capture safe, idempotent)
    hipFuncSetAttribute((const void*)scan_kernel,
                        hipFuncAttributeMaxDynamicSharedMemorySize, SMEM_BYTES);

    prep_kernel<<<512 + (B_ * L_) / CI_R, 256, 0, stream>>>(
        R_ig, obs, act, W_ci, b_ci, Rp, ci);
    scan_kernel<<<B_, D_, SMEM_BYTES, stream>>>((const uintx4*)Rp, ci, b_ig, W_out, b_out, out);
}

// Round 16
// 667.452 us; speedup vs baseline: 2.1343x; 2.1343x over previous
//
#include <hip/hip_runtime.h>

// Custom LSTM scan.  B=64, L=512, P=64, A=16, D=512, F=80.
//   h_t = h_{t-1} + tanh(x_t W_ci + b_ci) * sigmoid(h_{t-1} R_ig + b_ig)
//
// FINAL (R21) = R15 verbatim -- the best harness-verified kernel of the
// session (scan 533us, total 616us).  Session conclusion: the scan is
// LATENCY-bound, not BW/compute-bound.  Period = V + C_tail with
// V ~1900cy producer-side store->remote-visible fabric latency (probed
// 4 ways: poll strategy null [R13], sc1-only scope worse [R17], atomic
// publish -170cy [R15], compute-fill regressed [R18]) and C_tail ~500cy.
// Alternatives measured and rejected: row-pair fold (R14, 1.85x worse --
// rows are already parallel; wall-clock is the per-row period), single-CU
// R-resident (R0 803us; R16 dead; R20 1306us -- fdot2 can't read AGPRs,
// so the AGPR tier costs 128 accvgpr_reads/step inside a 128-VGPR
// envelope).  Structural scan floor ~510us = 512 serial steps x ~2400cy.
// Cross-session variance on identical code is ~11% (533 vs 593) -- only
// structural changes are measurable, and none with positive EV remain.
//
// Design: NQ=2 output split (128 WGs, 512 thr).  Per-thread R = 32 uint4
// = 128 regs, fully register-resident.  Cross-WG h exchange via
// self-tagged dwords (f16(h)<<16 | t+1): publish by global_atomic_swap
// sc1 (device scope, executes at the coherence point), poll by sc0sc1
// loads issued BEFORE the own-half dot phase (RT overlapped), batched
// 3-deep pipelined retry via vmcnt(2/1/0).  Parity-banked hbuf zeroed by
// prep each launch (graph-replay safe).  Tag freshness proof: same-parity
// tags never exceed t (partner's t+2 writes require all our t+1 posts,
// which follow our barrier A(t), which follows our tag-t reads).

#define B_  64
#define L_  512
#define P_  64
#define A_  16
#define D_  512
#define F_  80
#define CI_R 8

#define CI_BYTES   ((size_t)B_ * L_ * D_ * 2)        // 33,554,432
#define RP_BYTES   ((size_t)D_ * D_ * 2)             // 524,288
#define HBUF_UINTS (2 * B_ * 2 * 256)                // 65,536 (256 KB)
#define PBANK      ((size_t)B_ * 2 * 256)            // uints per parity bank
#define BATCH_CAP  4096

typedef _Float16 half2_t __attribute__((ext_vector_type(2)));
typedef unsigned int uintx4 __attribute__((ext_vector_type(4)));

__device__ __forceinline__ float dot2(unsigned int r, unsigned int h, float acc) {
    return __builtin_amdgcn_fdot2(__builtin_bit_cast(half2_t, h),
                                  __builtin_bit_cast(half2_t, r), acc, false);
}
__device__ __forceinline__ float dot4u(uintx4 r, uintx4 h, float acc) {
    acc = dot2(r.x, h.x, acc);
    acc = dot2(r.y, h.y, acc);
    acc = dot2(r.z, h.z, acc);
    acc = dot2(r.w, h.w, acc);
    return acc;
}
template<int CTRL>
__device__ __forceinline__ float dpp_mov(float v) {
    return __builtin_bit_cast(float, __builtin_amdgcn_update_dpp(
        0, __builtin_bit_cast(int, v), CTRL, 0xF, 0xF, true));
}
// DPP ctrls: 0xB1=xor1, 0x4E=xor2, 0x141=row_half_mirror(xor7),
// 0x140=row_mirror(xor15), 0x142=row_bcast15, 0x143=row_bcast31.

__device__ __forceinline__ unsigned int pk_f16(float a, float b) {
    return __builtin_bit_cast(unsigned int, __builtin_amdgcn_cvt_pkrtz(a, b));
}
__device__ __forceinline__ unsigned int ld_sc01(const unsigned int* p) {
    unsigned int v;
    asm volatile("global_load_dword %0, %1, off sc0 sc1\n\t"
                 "s_waitcnt vmcnt(0)" : "=v"(v) : "v"(p) : "memory");
    return v;
}
// publish via atomic swap: executes at the device coherence point (sc1 =
// device scope, cross-XCD coherent; no sc0 -> no return, fire-and-forget)
__device__ __forceinline__ void at_swap(unsigned int* p, unsigned int v) {
    asm volatile("global_atomic_swap %0, %1, off sc1" :: "v"(p), "v"(v) : "memory");
}
// rotation swizzle over 32 uint4 slots: block b=i>>3 rotates by b
__device__ __forceinline__ int swz4(int i) {
    return ((i >> 3) << 3) | ((i + (i >> 3)) & 7);
}

// Pack R_ig fp32[k][d] -> f16-pair uint chunks, layout [q][m][tid_s][dw]:
// chunk m = hh*16 + j*4 + c of thread tid_s (w,l,r,g) in WG-half q holds
// pairs for output d = q*256 + (w*8+r)*4 + j at
// k0 = hh*256 + (g&3)*64 + (g>>2)*32 + c*8 + 2*dw.
// Also zeroes hbuf (tags!) and out each launch (graph-replay safe).
__global__ __launch_bounds__(256) void prep_kernel(const float* __restrict__ R,
        unsigned int* __restrict__ Rp, unsigned int* __restrict__ hbuf,
        float* __restrict__ out) {
    int id = blockIdx.x * 256 + threadIdx.x;          // 131072 uints
    int dw = id & 3;
    int U = id >> 2;
    int tid_s = U & 511;
    int m  = (U >> 9) & 31;
    int qq = U >> 14;
    int w = tid_s >> 6, l = tid_s & 63, r = l >> 3, g = l & 7;
    int hh = m >> 4, j = (m >> 2) & 3, c = m & 3;
    int d  = qq * 256 + (w * 8 + r) * 4 + j;
    int k0 = hh * 256 + (g & 3) * 64 + (g >> 2) * 32 + c * 8 + 2 * dw;
    half2_t v;
    v.x = (_Float16)R[k0 * D_ + d];
    v.y = (_Float16)R[(k0 + 1) * D_ + d];
    Rp[id] = __builtin_bit_cast(unsigned int, v);
    if (id < HBUF_UINTS) hbuf[id] = 0u;
    if (id < B_ * L_) out[id] = 0.f;
}

// ci = tanh(x @ W_ci + b_ci), stored f16.  One block does CI_R (b,l) rows.
__global__ __launch_bounds__(256) void ci_kernel(const float* __restrict__ obs,
                                                 const float* __restrict__ act,
                                                 const float* __restrict__ W,
                                                 const float* __restrict__ bci,
                                                 unsigned short* __restrict__ ci) {
    __shared__ float xs[CI_R][F_];
    int row0 = blockIdx.x * CI_R;
    int tid = threadIdx.x;
    for (int idx = tid; idx < CI_R * F_; idx += 256) {
        int r = idx / F_, f = idx % F_;
        float v = (f < P_) ? obs[(size_t)(row0 + r) * P_ + f]
                           : act[(size_t)(row0 + r) * A_ + (f - P_)];
        xs[r][f] = v;
    }
    __syncthreads();
    int d0 = tid, d1 = tid + 256;
    float a0[CI_R], a1[CI_R];
    #pragma unroll
    for (int r = 0; r < CI_R; ++r) { a0[r] = 0.f; a1[r] = 0.f; }
    for (int f = 0; f < F_; ++f) {
        float w0 = W[f * D_ + d0];
        float w1 = W[f * D_ + d1];
        #pragma unroll
        for (int r = 0; r < CI_R; ++r) {
            float xv = xs[r][f];
            a0[r] += xv * w0;
            a1[r] += xv * w1;
        }
    }
    float b0 = bci[d0], b1 = bci[d1];
    #pragma unroll
    for (int r = 0; r < CI_R; ++r) {
        float z0 = a0[r] + b0, z1 = a1[r] + b1;
        float e0 = __expf(-2.f * __builtin_fabsf(z0));
        float e1 = __expf(-2.f * __builtin_fabsf(z1));
        float m0 = (1.f - e0) * __builtin_amdgcn_rcpf(1.f + e0);
        float m1 = (1.f - e1) * __builtin_amdgcn_rcpf(1.f + e1);
        float t0 = z0 < 0.f ? -m0 : m0;
        float t1 = z1 < 0.f ? -m1 : m1;
        ci[(size_t)(row0 + r) * D_ + d0] = __builtin_bit_cast(unsigned short, (_Float16)t0);
        ci[(size_t)(row0 + r) * D_ + d1] = __builtin_bit_cast(unsigned short, (_Float16)t1);
    }
}

// Serial scan, 2 WGs per batch row.  WG (row,q) owns d in [q*256,+256).
// Thread (w,l,r,g): 4 outputs d = q*256+(w*8+r)*4+j; partials over
// k in [hh*256+(g&3)*64+(g>>2)*32, +32) for hh=q (phase2, hp2) and
// hh=1-q (phase5, hst).  8-lane DPP full reduce; lane owns j=g&3.
// rr[0..15]=own-half chunks, rr[16..31]=remote (pre-swapped by q).
__global__ __launch_bounds__(512, 2)
__attribute__((amdgpu_waves_per_eu(2, 2)))
void scan_kernel(const unsigned int* __restrict__ Rp,
                 const unsigned short* __restrict__ ci,
                 const float* __restrict__ b_ig, const float* __restrict__ W_out,
                 const float* __restrict__ b_out, float* __restrict__ out,
                 unsigned int* __restrict__ hbuf)
{
    const int tid = threadIdx.x;
    const int bid = blockIdx.x;
    const int row = bid & 63;
    const int q   = bid >> 6;
    const int w = tid >> 6;
    const int l = tid & 63;
    const int r = l >> 3;
    const int g = l & 7;
    const int g3 = g & 3;

    __shared__ __align__(16) unsigned int hp2[128];   // own-half h pairs, swizzled
    __shared__ __align__(16) unsigned int hst[128];   // remote-half h pairs, swizzled

    // rr pre-swapped: rr[mm] = chunk (mm ^ (q<<4)) -> rr[0..15] own half
    const uintx4* tb = (const uintx4*)Rp + (size_t)q * 16384 + tid;
    const int qx = q << 4;
    uintx4 rr[32];
    #pragma unroll
    for (int mm = 0; mm < 32; ++mm) rr[mm] = tb[(mm ^ qx) * 512];
    #pragma unroll
    for (int mm = 0; mm < 32; ++mm) asm volatile("" : "+v"(rr[mm]));

    const int dloc = (w * 8 + r) * 4 + g3;
    const int down = q * 256 + dloc;
    const float bg = b_ig[down];
    const float wo = W_out[down];
    const float bo = b_out[0];
    const unsigned short* cip = ci + (size_t)row * L_ * D_ + down;

    // hp2 writer slot (lanes g in {0,2}): pair u = (w*8+r)*2 + (g>>1)
    const int u_own = (w * 8 + r) * 2 + (g >> 1);
    const int wslot = swz4(u_own >> 2) * 4 + (u_own & 3);
    // hst fetcher slot: s=tid<256, pair u=s>>1, even lanes write packed dword
    const int s_f = tid & 255;
    const int stslot = swz4(s_f >> 3) * 4 + ((s_f >> 1) & 3);
    // h-read uint4 base index: i = (g&3)*8 + (g>>2)*4 + c
    const int ib = (g & 3) * 8 + (g >> 2) * 4;
    const int ri0 = swz4(ib + 0), ri1 = swz4(ib + 1);
    const int ri2 = swz4(ib + 2), ri3 = swz4(ib + 3);

    const unsigned int* rdbase = hbuf + ((size_t)row * 2 + (1 - q)) * 256 + s_f;
    unsigned int* wrbase = hbuf + ((size_t)row * 2 + q) * 256 + dloc;

    float hval = 0.f;
    __syncthreads();

    #pragma unroll 1
    for (int t = 0; t < L_; ++t) {
        unsigned short cu = cip[(size_t)t * D_];   // issue early

        // issue tagged fetch (no wait) -- RT overlaps own-half dots
        unsigned int vfetch = 0;
        const unsigned int* src = rdbase + (size_t)((t - 1) & 1) * PBANK;
        if (t > 0 && tid < 256) {
            asm volatile("global_load_dword %0, %1, off sc0 sc1"
                         : "=&v"(vfetch) : "v"(src) : "memory");
        }

        float p0 = 0.f, p1 = 0.f, p2 = 0.f, p3 = 0.f;

        // phase2: own-half dots from hp2 (written at tail(t-1), behind B)
        if (t > 0) {
            const uintx4* hp4 = (const uintx4*)hp2;
            uintx4 h0 = hp4[ri0], h1 = hp4[ri1], h2 = hp4[ri2], h3 = hp4[ri3];
            p0 = dot4u(rr[0],  h0, p0); p0 = dot4u(rr[1],  h1, p0);
            p0 = dot4u(rr[2],  h2, p0); p0 = dot4u(rr[3],  h3, p0);
            p1 = dot4u(rr[4],  h0, p1); p1 = dot4u(rr[5],  h1, p1);
            p1 = dot4u(rr[6],  h2, p1); p1 = dot4u(rr[7],  h3, p1);
            p2 = dot4u(rr[8],  h0, p2); p2 = dot4u(rr[9],  h1, p2);
            p2 = dot4u(rr[10], h2, p2); p2 = dot4u(rr[11], h3, p2);
            p3 = dot4u(rr[12], h0, p3); p3 = dot4u(rr[13], h1, p3);
            p3 = dot4u(rr[14], h2, p3); p3 = dot4u(rr[15], h3, p3);
        }

        // phase3: finish fetch; if stale, batched pipelined poll (3 loads
        // spaced by s_sleep, checked oldest-first via vmcnt(2/1/0)).
        if (t > 0 && tid < 256) {
            asm volatile("s_waitcnt vmcnt(0)" : "+v"(vfetch) :: "memory");
            const unsigned int tt = (unsigned int)t;
            if ((vfetch & 0xffffu) != tt) {
                int it = 0;
                unsigned int a0, a1, a2;
                for (;;) {
                    asm volatile("global_load_dword %0, %1, off sc0 sc1"
                                 : "=&v"(a0) : "v"(src) : "memory");
                    __builtin_amdgcn_s_sleep(1);
                    asm volatile("global_load_dword %0, %1, off sc0 sc1"
                                 : "=&v"(a1) : "v"(src) : "memory");
                    __builtin_amdgcn_s_sleep(1);
                    asm volatile("global_load_dword %0, %1, off sc0 sc1"
                                 : "=&v"(a2) : "v"(src) : "memory");
                    asm volatile("s_waitcnt vmcnt(2)" ::: "memory");
                    if ((a0 & 0xffffu) == tt) {
                        vfetch = a0;
                        asm volatile("s_waitcnt vmcnt(0)" ::: "memory");
                        break;
                    }
                    asm volatile("s_waitcnt vmcnt(1)" ::: "memory");
                    if ((a1 & 0xffffu) == tt) {
                        vfetch = a1;
                        asm volatile("s_waitcnt vmcnt(0)" ::: "memory");
                        break;
                    }
                    asm volatile("s_waitcnt vmcnt(0)" ::: "memory");
                    if ((a2 & 0xffffu) == tt) { vfetch = a2; break; }
                    if (++it > BATCH_CAP) break;       // finite fail, no hang
                    __builtin_amdgcn_s_sleep(1);
                }
            }
            unsigned int vo = __builtin_bit_cast(unsigned int,
                                dpp_mov<0xB1>(__builtin_bit_cast(float, vfetch)));
            if ((tid & 1) == 0)
                hst[stslot] = (vfetch >> 16) | (vo & 0xffff0000u);
        }

        // barrier A: hst visible; separates phase2 reads from hp2 rewrite
        asm volatile("s_waitcnt lgkmcnt(0)" ::: "memory");
        __builtin_amdgcn_s_barrier();
        asm volatile("" ::: "memory");

        // phase5: remote-half dots from hst
        if (t > 0) {
            const uintx4* hs4 = (const uintx4*)hst;
            uintx4 h0 = hs4[ri0], h1 = hs4[ri1], h2 = hs4[ri2], h3 = hs4[ri3];
            p0 = dot4u(rr[16], h0, p0); p0 = dot4u(rr[17], h1, p0);
            p0 = dot4u(rr[18], h2, p0); p0 = dot4u(rr[19], h3, p0);
            p1 = dot4u(rr[20], h0, p1); p1 = dot4u(rr[21], h1, p1);
            p1 = dot4u(rr[22], h2, p1); p1 = dot4u(rr[23], h3, p1);
            p2 = dot4u(rr[24], h0, p2); p2 = dot4u(rr[25], h1, p2);
            p2 = dot4u(rr[26], h2, p2); p2 = dot4u(rr[27], h3, p2);
            p3 = dot4u(rr[28], h0, p3); p3 = dot4u(rr[29], h1, p3);
            p3 = dot4u(rr[30], h2, p3); p3 = dot4u(rr[31], h3, p3);
        }

        // 8-lane full reduce (xor7, xor1, xor2) per accumulator
        float s0 = p0 + dpp_mov<0x141>(p0);
        float s1 = p1 + dpp_mov<0x141>(p1);
        float s2 = p2 + dpp_mov<0x141>(p2);
        float s3 = p3 + dpp_mov<0x141>(p3);
        s0 = s0 + dpp_mov<0xB1>(s0);  s1 = s1 + dpp_mov<0xB1>(s1);
        s2 = s2 + dpp_mov<0xB1>(s2);  s3 = s3 + dpp_mov<0xB1>(s3);
        s0 = s0 + dpp_mov<0x4E>(s0);  s1 = s1 + dpp_mov<0x4E>(s1);
        s2 = s2 + dpp_mov<0x4E>(s2);  s3 = s3 + dpp_mov<0x4E>(s3);
        float z = ((g3 & 2) ? ((g3 & 1) ? s3 : s2)
                            : ((g3 & 1) ? s1 : s0)) + bg;

        float ig  = __builtin_amdgcn_rcpf(1.f + __expf(-z));
        float civ = (float)__builtin_bit_cast(_Float16, cu);
        hval += civ * ig;

        // publish tagged h IMMEDIATELY via atomic swap (g<4, device scope)
        if (g < 4) {
            unsigned int hb = pk_f16(hval, hval) & 0xffffu;
            at_swap(wrbase + (size_t)(t & 1) * PBANK,
                    (hb << 16) | (unsigned int)(t + 1));
        }

        // own-half pair publish to hp2 (writers g in {0,2})
        float nbh = dpp_mov<0xB1>(hval);   // lane^1 = odd-d neighbor
        if (g == 0 || g == 2) {
            hp2[wslot] = pk_f16(hval, nbh);
        }

        // barrier B: hp2 writes ordered before next step's phase2 reads
        asm volatile("s_waitcnt lgkmcnt(0)" ::: "memory");
        __builtin_amdgcn_s_barrier();
        asm volatile("" ::: "memory");

        // out[t] commit, post-B (off the critical chain)
        float po = (g < 4) ? hval * wo : 0.f;
        po += dpp_mov<0xB1>(po);
        po += dpp_mov<0x4E>(po);
        po += dpp_mov<0x141>(po);
        po += dpp_mov<0x140>(po);
        po += dpp_mov<0x142>(po);
        po += dpp_mov<0x143>(po);
        if (l == 63) {
            float addv = po + ((q == 0 && w == 0) ? bo : 0.f);
            atomicAdd(out + row * L_ + t, addv);
        }
    }
}

extern "C" void kernel_launch(void* const* d_in, const int* in_sizes, int n_in,
                              void* d_out, int out_size, void* d_ws, size_t ws_size,
                              hipStream_t stream) {
    const float* obs   = (const float*)d_in[0];
    const float* act   = (const float*)d_in[1];
    const float* W_ci  = (const float*)d_in[2];
    const float* b_ci  = (const float*)d_in[3];
    const float* R_ig  = (const float*)d_in[4];
    const float* b_ig  = (const float*)d_in[5];
    const float* W_out = (const float*)d_in[6];
    const float* b_out = (const float*)d_in[7];
    float* out = (float*)d_out;

    unsigned short* ci = (unsigned short*)d_ws;
    unsigned int* Rp   = (unsigned int*)((char*)d_ws + CI_BYTES);
    unsigned int* hbuf = (unsigned int*)((char*)d_ws + CI_BYTES + RP_BYTES);

    prep_kernel<<<512, 256, 0, stream>>>(R_ig, Rp, hbuf, out);
    ci_kernel<<<(B_ * L_) / CI_R, 256, 0, stream>>>(obs, act, W_ci, b_ci, ci);
    scan_kernel<<<B_ * 2, 512, 0, stream>>>(Rp, ci, b_ig, W_out, b_out, out, hbuf);
}